// Round 13
// baseline (159.041 us; speedup 1.0000x reference)
//
#include <hip/hip_runtime.h>
#include <stdint.h>

// Problem constants (fixed by reference setup_inputs): B=4096, D=512, L=80
#define B_ROWS 4096
#define DIMS   512
#define NLAB   80
#define HALF_ROWS 2048
#define HCNT   8388608u   // B*B/2 = 2^23, threefry counter split point
#define CHUNK  1024       // j-range per sub-wave
#define SEGCAP 256u       // per-(row,sub) S-segment capacity in LDS

typedef unsigned long long u64;

__device__ __forceinline__ uint32_t rotl32(uint32_t x, uint32_t d) {
    return (x << d) | (x >> (32u - d));
}

// JAX threefry2x32 with key = (0, 42)
__device__ __forceinline__ void tf2x32_key42(uint32_t c0, uint32_t c1,
                                             uint32_t& o0, uint32_t& o1) {
    const uint32_t ks0 = 0u;
    const uint32_t ks1 = 42u;
    const uint32_t ks2 = 0x1BD11BDAu ^ 0u ^ 42u;
    uint32_t x0 = c0 + ks0;
    uint32_t x1 = c1 + ks1;
#define TF_RND(r) { x0 += x1; x1 = rotl32(x1, (r)); x1 ^= x0; }
    TF_RND(13u) TF_RND(15u) TF_RND(26u) TF_RND(6u)
    x0 += ks1; x1 += ks2 + 1u;
    TF_RND(17u) TF_RND(29u) TF_RND(16u) TF_RND(24u)
    x0 += ks2; x1 += ks0 + 2u;
    TF_RND(13u) TF_RND(15u) TF_RND(26u) TF_RND(6u)
    x0 += ks0; x1 += ks1 + 3u;
    TF_RND(17u) TF_RND(29u) TF_RND(16u) TF_RND(24u)
    x0 += ks1; x1 += ks2 + 4u;
    TF_RND(13u) TF_RND(15u) TF_RND(26u) TF_RND(6u)
    x0 += ks2; x1 += ks0 + 5u;
#undef TF_RND
    o0 = x0; o1 = x1;
}

__device__ __forceinline__ u64 shflx64(u64 v, int m) {
    uint32_t lo = __shfl_xor((uint32_t)(v & 0xFFFFFFFFull), m, 64);
    uint32_t hi = __shfl_xor((uint32_t)(v >> 32), m, 64);
    return ((u64)hi << 32) | (u64)lo;
}

__device__ __forceinline__ uint32_t umx(uint32_t a, uint32_t b) { return a > b ? a : b; }
__device__ __forceinline__ uint32_t umn(uint32_t a, uint32_t b) { return a < b ? a : b; }

// unconditional sorted-desc insert: t[4]=max(t[4],k), bubble (8 min/max)
__device__ __forceinline__ void ins5_u32(uint32_t* t, uint32_t k) {
    t[4] = umx(t[4], k);
    uint32_t hi, lo;
    hi = umx(t[3], t[4]); lo = umn(t[3], t[4]); t[3] = hi; t[4] = lo;
    hi = umx(t[2], t[3]); lo = umn(t[2], t[3]); t[2] = hi; t[3] = lo;
    hi = umx(t[1], t[2]); lo = umn(t[1], t[2]); t[1] = hi; t[2] = lo;
    hi = umx(t[0], t[1]); lo = umn(t[0], t[1]); t[0] = hi; t[1] = lo;
}

// merge two sorted-desc 5-lists, keep top-5 (min/max network) — scalar use only
__device__ __forceinline__ void merge5_u32(uint32_t* A, const uint32_t* Bv) {
    uint32_t a0=A[0],a1=A[1],a2=A[2],a3=A[3],a4=A[4];
    uint32_t b0=Bv[0],b1=Bv[1],b2=Bv[2],b3=Bv[3],b4=Bv[4];
    uint32_t m0 = umx(a0, b0);
    uint32_t m1 = umx(umx(a1, b1), umn(a0, b0));
    uint32_t m2 = umx(umx(a2, b2), umx(umn(a0, b1), umn(a1, b0)));
    uint32_t m3 = umx(umx(a3, b3), umx(umx(umn(a0, b2), umn(a1, b1)), umn(a2, b0)));
    uint32_t m4 = umx(umx(a4, b4), umx(umx(umn(a0, b3), umn(a1, b2)),
                                       umx(umn(a2, b1), umn(a3, b0))));
    A[0]=m0; A[1]=m1; A[2]=m2; A[3]=m3; A[4]=m4;
}

// wave-wide top-5 of 64 per-lane sorted-desc 5-lists via 5x (wave-max + pop).
// Identical to butterfly multiset-merge because real keys are index-tagged
// (globally unique); only filler/zero keys duplicate across lanes and those
// can never displace real entries (real key19 >= 1 > 0).
__device__ __forceinline__ void wave_top5_2(uint32_t* ta, uint32_t* tb,
                                            uint32_t* fa, uint32_t* fb) {
#pragma unroll
    for (int k = 0; k < 5; ++k) {
        uint32_t ma = ta[0], mb = tb[0];
#pragma unroll
        for (int s = 1; s < 64; s <<= 1) {
            ma = umx(ma, __shfl_xor(ma, s, 64));
            mb = umx(mb, __shfl_xor(mb, s, 64));
        }
        fa[k] = ma; fb[k] = mb;
        if (ta[0] == ma) { ta[0]=ta[1]; ta[1]=ta[2]; ta[2]=ta[3]; ta[3]=ta[4]; ta[4]=0u; }
        if (tb[0] == mb) { tb[0]=tb[1]; tb[1]=tb[2]; tb[2]=tb[3]; tb[3]=tb[4]; tb[4]=0u; }
    }
}

__device__ __forceinline__ void wave_top5_1(uint32_t* t, uint32_t* f) {
#pragma unroll
    for (int k = 0; k < 5; ++k) {
        uint32_t m = t[0];
#pragma unroll
        for (int s = 1; s < 64; s <<= 1) m = umx(m, __shfl_xor(m, s, 64));
        f[k] = m;
        if (t[0] == m) { t[0]=t[1]; t[1]=t[2]; t[2]=t[3]; t[3]=t[4]; t[4]=0u; }
    }
}

// exact key19 = floor(it*2^19/u) + 1  (rcp seed, 1-ULP -> +/-1 fixup suffices)
__device__ __forceinline__ uint32_t jkey19(uint32_t it, uint32_t u) {
    const uint32_t n = it << 19;
    float f = (float)it * __builtin_amdgcn_rcpf((float)u) * 524288.0f;
    uint32_t ak = (uint32_t)f;
    int r = (int)(n - ak * u);
    if (r < 0) { ak--; r += (int)u; }
    if (r >= (int)u) ak++;
    return ak + 1u;
}

// ---------------- kernels ----------------

// pack labels (ballot) + row norms. 1 wave per row.
__global__ __launch_bounds__(256) void prep_kernel(const float* __restrict__ x,
                                                   const int* __restrict__ labels,
                                                   uint4* __restrict__ pk,
                                                   float* __restrict__ norms) {
    const int tid = threadIdx.x;
    const int lane = tid & 63;
    const int row = blockIdx.x * 4 + (tid >> 6);
    const int* lr = labels + (size_t)row * NLAB;
    const int la = lr[lane];
    const int lb = (lane < 16) ? lr[64 + lane] : 0;
    const u64 b0 = __ballot(la != 0);
    const u64 b1 = __ballot(lb != 0);          // lanes >=16 contribute 0
    const uint32_t w2 = (uint32_t)b1 & 0xFFFFu;
    const uint32_t cnt = (uint32_t)__popcll(b0) + (uint32_t)__popc(w2);
    if (lane == 0) pk[row] = make_uint4((uint32_t)b0, (uint32_t)(b0 >> 32), w2, cnt);
    const float* xr = x + (size_t)row * DIMS;
    float ss = 0.f;
#pragma unroll
    for (int u = 0; u < 8; ++u) { float v = xr[lane + 64 * u]; ss += v * v; }
#pragma unroll
    for (int m = 1; m < 64; m <<= 1) ss += __shfl_xor(ss, m, 64);
    if (lane == 0) norms[row] = fmaxf(sqrtf(ss), 1e-12f);
}

// FUSED kernel: one ROW-PAIR per 256-thr block (grid 2048). R9 body with
// (a) wave-max-pop top-5 extraction replacing butterfly merges, and
// (b) atomic finalize (last block computes the mean) — no final kernel.
__global__ __launch_bounds__(256) void fused_kernel(const float* __restrict__ x,
                                                    const uint4* __restrict__ pk,
                                                    const float* __restrict__ norms,
                                                    float* __restrict__ acc,
                                                    uint32_t* __restrict__ ticket,
                                                    float* __restrict__ out) {
    __shared__ uint32_t segL[2][4][SEGCAP];   // 8 KB
    __shared__ uint32_t cntL[2][4];
    __shared__ uint32_t keysL[2][4][5];
    __shared__ uint32_t tgL[2][6];
    __shared__ uint32_t validL[2];
    __shared__ float    simsL[2][6];
    __shared__ float    lossW[2], cntW2[2];

    const int tid = threadIdx.x;
    const int lane = tid & 63;
    const int sub  = tid >> 6;                 // 0..3 = j-slice
    const int pr   = (int)blockIdx.x;          // [0,2048)
    const int r0 = pr, r1 = pr + HALF_ROWS;
    const uint4 P0 = pk[r0], P1 = pk[r1];
    const uint32_t cw0 = P0.w, cw1 = P1.w;
    const int jbase = sub * CHUNK;

    // ---- scan own slice, both rows of the pair ----
    uint32_t cnt0 = 0u, cnt1 = 0u;
    uint32_t t0[5], t1[5];
#pragma unroll
    for (int k = 0; k < 5; ++k) {
        const uint32_t fk = (uint32_t)(~(jbase + k)) & 0xFFFu;   // -inf fillers
        t0[k] = fk; t1[k] = fk;
    }
    uint32_t thr0 = umx(t0[4] >> 12, 1u) - 1u;
    uint32_t thr1 = umx(t1[4] >> 12, 1u) - 1u;

#pragma unroll 4
    for (int jb = 0; jb < CHUNK; jb += 64) {
        const int j = jbase + jb + lane;
        const uint4 pj = pk[j];                // L2-resident (64 KB table)
        const uint32_t cj = pj.w;
        const uint32_t jx = (~(uint32_t)j) & 0xFFFu;
        const uint32_t it0 = (uint32_t)(__popc(P0.x & pj.x) + __popc(P0.y & pj.y) + __popc(P0.z & pj.z));
        const uint32_t u0  = cw0 + cj - it0;
        const uint32_t it1 = (uint32_t)(__popc(P1.x & pj.x) + __popc(P1.y & pj.y) + __popc(P1.z & pj.z));
        const uint32_t u1  = cw1 + cj - it1;
        const bool c0 = (it0 << 1) > u0;
        const bool c1 = (it1 << 1) > u1;
        const u64 bal0 = __ballot(c0);
        const u64 bal1 = __ballot(c1);
        const u64 lmask = (1ull << lane) - 1ull;
        if (c0) {
            const uint32_t off = cnt0 + (uint32_t)__popcll(bal0 & lmask);
            if (off < SEGCAP) segL[0][sub][off] = (it0 << 20) | (u0 << 12) | (uint32_t)j;
        } else if ((it0 << 19) >= __umul24(thr0, u0)) {
            ins5_u32(t0, (jkey19(it0, u0) << 12) | jx);
            thr0 = umx(t0[4] >> 12, 1u) - 1u;
        }
        cnt0 += (uint32_t)__popcll(bal0);
        if (c1) {
            const uint32_t off = cnt1 + (uint32_t)__popcll(bal1 & lmask);
            if (off < SEGCAP) segL[1][sub][off] = (it1 << 20) | (u1 << 12) | (uint32_t)j;
        } else if ((it1 << 19) >= __umul24(thr1, u1)) {
            ins5_u32(t1, (jkey19(it1, u1) << 12) | jx);
            thr1 = umx(t1[4] >> 12, 1u) - 1u;
        }
        cnt1 += (uint32_t)__popcll(bal1);
    }
    // wave-max-pop extraction (uniform result); lane 0 publishes
    {
        uint32_t f0[5], f1[5];
        wave_top5_2(t0, t1, f0, f1);
        if (lane == 0) {
            cntL[0][sub] = cnt0; cntL[1][sub] = cnt1;
#pragma unroll
            for (int k = 0; k < 5; ++k) { keysL[0][sub][k] = f0[k]; keysL[1][sub][k] = f1[k]; }
        }
    }
    __syncthreads();

    // ---- waves 0/1: selection for row h = sub ----
    if (sub < 2) {
        const int h = sub;
        uint32_t f[5];
#pragma unroll
        for (int k = 0; k < 5; ++k) f[k] = keysL[h][0][k];
#pragma unroll
        for (int s = 1; s < 4; ++s) {
            uint32_t o[5];
#pragma unroll
            for (int k = 0; k < 5; ++k) o[k] = keysL[h][s][k];
            merge5_u32(f, o);
        }
        uint32_t ns[4];
#pragma unroll
        for (int s = 0; s < 4; ++s) ns[s] = umn(cntL[h][s], SEGCAP);

        // phase A: gumbel argmax over S entries (key19 payload in low bits)
        const uint32_t base23 = (uint32_t)pr * (uint32_t)B_ROWS;
        u64 gb = 0ull;
#pragma unroll
        for (int s = 0; s < 4; ++s) {
            for (int e = lane; e < (int)ns[s]; e += 64) {
                const uint32_t ent = segL[h][s][e];
                const uint32_t j  = ent & 0xFFFu;
                const uint32_t u  = (ent >> 12) & 0xFFu;
                const uint32_t it = ent >> 20;
                uint32_t o0, o1;
                tf2x32_key42(base23 + j, base23 + j + HCNT, o0, o1);
                const uint32_t o = h ? o1 : o0;
                const u64 key = ((u64)(o >> 9) << 41) | ((u64)((~j) & 0xFFFu) << 29) | (u64)jkey19(it, u);
                if (key > gb) gb = key;
            }
        }
#pragma unroll
        for (int m = 1; m < 64; m <<= 1) {
            const u64 o = shflx64(gb, m);
            if (o > gb) gb = o;
        }
        const bool valid = gb != 0ull;
        const int pos = valid ? (int)((~(uint32_t)(gb >> 29)) & 0xFFFu) : 0;
        const uint32_t pjkey = (uint32_t)(gb & 0xFFFFFu);

        // phase B: top-5 of S-members strictly below pj
        uint32_t ts[5] = {0u, 0u, 0u, 0u, 0u};
#pragma unroll
        for (int s = 0; s < 4; ++s) {
            for (int e = lane; e < (int)ns[s]; e += 64) {
                const uint32_t ent = segL[h][s][e];
                const uint32_t j  = ent & 0xFFFu;
                const uint32_t u  = (ent >> 12) & 0xFFu;
                const uint32_t it = ent >> 20;
                const uint32_t k19 = jkey19(it, u);
                if (k19 < pjkey) ins5_u32(ts, (k19 << 12) | ((~j) & 0xFFFu));
            }
        }
        uint32_t tsf[5];
        wave_top5_1(ts, tsf);
        merge5_u32(f, tsf);   // S keys (>0.5) outrank non-S keys; exact order

        if (lane == 0) {
            tgL[h][0] = (uint32_t)pos;
#pragma unroll
            for (int k = 0; k < 5; ++k) tgL[h][k + 1] = (~f[k]) & 0xFFFu;
            validL[h] = valid ? 1u : 0u;
        }
    }
    __syncthreads();

    // ---- 12 gather-dots, 3 per wave (identical fp order to R9) ----
#pragma unroll
    for (int k = 0; k < 3; ++k) {
        const int d = sub + 4 * k;
        const int h = (d >= 6) ? 1 : 0;
        const int q = d - 6 * h;
        const int row = h ? r1 : r0;
        const int tgt = (int)tgL[h][q];
        const float* pa = x + (size_t)row * DIMS;
        const float* pb = x + (size_t)tgt * DIMS;
        float s = 0.f;
#pragma unroll
        for (int u = 0; u < 8; ++u) s += pa[lane + 64 * u] * pb[lane + 64 * u];
#pragma unroll
        for (int m = 1; m < 64; m <<= 1) s += __shfl_xor(s, m, 64);
        if (lane == 0) simsL[h][q] = s;
    }
    __syncthreads();

    if (sub < 2 && lane == 0) {
        const int h = sub;
        float loss = 0.f, cnt = 0.f;
        if (validL[h]) {
            const int row = h ? r1 : r0;
            const float nr = norms[row];
            const float sp = simsL[h][0] / (nr * norms[tgL[h][0]]);
            float sen = 0.f;
#pragma unroll
            for (int q = 1; q < 6; ++q) sen += expf(simsL[h][q] / (nr * norms[tgL[h][q]]));
            const float ep = expf(sp);
            loss = -logf(ep / (ep + sen));
            cnt = 1.f;
        }
        lossW[h] = loss; cntW2[h] = cnt;
    }
    __syncthreads();

    // ---- atomic finalize: last block computes the mean ----
    if (tid == 0) {
        atomicAdd(&acc[0], lossW[0] + lossW[1]);
        atomicAdd(&acc[1], cntW2[0] + cntW2[1]);
        __threadfence();
        const uint32_t old = atomicAdd(ticket, 1u);
        if (old == 2047u) {
            const float L = atomicAdd(&acc[0], 0.0f);   // coherent read
            const float C = atomicAdd(&acc[1], 0.0f);
            out[0] = L / C;
        }
    }
}

extern "C" void kernel_launch(void* const* d_in, const int* in_sizes, int n_in,
                              void* d_out, int out_size, void* d_ws, size_t ws_size,
                              hipStream_t stream) {
    const float* x      = (const float*)d_in[0];
    const int*   labels = (const int*)d_in[1];
    float* out = (float*)d_out;

    char* ws = (char*)d_ws;
    float*    acc    = (float*)ws;                    // acc[0]=loss, acc[1]=cnt
    uint32_t* ticket = (uint32_t*)(ws + 8);           // completion counter
    uint4*    pk     = (uint4*)(ws + 256);            // 64 KB
    float*    norms  = (float*)(ws + 256 + 65536);    // 16 KB

    hipMemsetAsync(ws, 0, 16, stream);                // zero acc + ticket
    hipLaunchKernelGGL(prep_kernel,  dim3(1024), dim3(256), 0, stream, x, labels, pk, norms);
    hipLaunchKernelGGL(fused_kernel, dim3(2048), dim3(256), 0, stream, x, pk, norms,
                       acc, ticket, out);
}

// Round 14
// 99.152 us; speedup vs baseline: 1.6040x; 1.6040x over previous
//
#include <hip/hip_runtime.h>
#include <stdint.h>

// Problem constants (fixed by reference setup_inputs): B=4096, D=512, L=80
#define B_ROWS 4096
#define DIMS   512
#define NLAB   80
#define HALF_ROWS 2048
#define HCNT   8388608u   // B*B/2 = 2^23, threefry counter split point
#define CHUNK  1024       // j-range per sub-wave
#define SEGCAP 256u       // per-(row,sub) S-segment capacity in LDS

typedef unsigned long long u64;

__device__ __forceinline__ uint32_t rotl32(uint32_t x, uint32_t d) {
    return (x << d) | (x >> (32u - d));
}

// JAX threefry2x32 with key = (0, 42)
__device__ __forceinline__ void tf2x32_key42(uint32_t c0, uint32_t c1,
                                             uint32_t& o0, uint32_t& o1) {
    const uint32_t ks0 = 0u;
    const uint32_t ks1 = 42u;
    const uint32_t ks2 = 0x1BD11BDAu ^ 0u ^ 42u;
    uint32_t x0 = c0 + ks0;
    uint32_t x1 = c1 + ks1;
#define TF_RND(r) { x0 += x1; x1 = rotl32(x1, (r)); x1 ^= x0; }
    TF_RND(13u) TF_RND(15u) TF_RND(26u) TF_RND(6u)
    x0 += ks1; x1 += ks2 + 1u;
    TF_RND(17u) TF_RND(29u) TF_RND(16u) TF_RND(24u)
    x0 += ks2; x1 += ks0 + 2u;
    TF_RND(13u) TF_RND(15u) TF_RND(26u) TF_RND(6u)
    x0 += ks0; x1 += ks1 + 3u;
    TF_RND(17u) TF_RND(29u) TF_RND(16u) TF_RND(24u)
    x0 += ks1; x1 += ks2 + 4u;
    TF_RND(13u) TF_RND(15u) TF_RND(26u) TF_RND(6u)
    x0 += ks2; x1 += ks0 + 5u;
#undef TF_RND
    o0 = x0; o1 = x1;
}

__device__ __forceinline__ u64 shflx64(u64 v, int m) {
    uint32_t lo = __shfl_xor((uint32_t)(v & 0xFFFFFFFFull), m, 64);
    uint32_t hi = __shfl_xor((uint32_t)(v >> 32), m, 64);
    return ((u64)hi << 32) | (u64)lo;
}

__device__ __forceinline__ uint32_t umx(uint32_t a, uint32_t b) { return a > b ? a : b; }
__device__ __forceinline__ uint32_t umn(uint32_t a, uint32_t b) { return a < b ? a : b; }

// unconditional sorted-desc insert: t[4]=max(t[4],k), bubble (8 min/max)
__device__ __forceinline__ void ins5_u32(uint32_t* t, uint32_t k) {
    t[4] = umx(t[4], k);
    uint32_t hi, lo;
    hi = umx(t[3], t[4]); lo = umn(t[3], t[4]); t[3] = hi; t[4] = lo;
    hi = umx(t[2], t[3]); lo = umn(t[2], t[3]); t[2] = hi; t[3] = lo;
    hi = umx(t[1], t[2]); lo = umn(t[1], t[2]); t[1] = hi; t[2] = lo;
    hi = umx(t[0], t[1]); lo = umn(t[0], t[1]); t[0] = hi; t[1] = lo;
}

// merge two sorted-desc 5-lists, keep top-5 (min/max network) — scalar use only
__device__ __forceinline__ void merge5_u32(uint32_t* A, const uint32_t* Bv) {
    uint32_t a0=A[0],a1=A[1],a2=A[2],a3=A[3],a4=A[4];
    uint32_t b0=Bv[0],b1=Bv[1],b2=Bv[2],b3=Bv[3],b4=Bv[4];
    uint32_t m0 = umx(a0, b0);
    uint32_t m1 = umx(umx(a1, b1), umn(a0, b0));
    uint32_t m2 = umx(umx(a2, b2), umx(umn(a0, b1), umn(a1, b0)));
    uint32_t m3 = umx(umx(a3, b3), umx(umx(umn(a0, b2), umn(a1, b1)), umn(a2, b0)));
    uint32_t m4 = umx(umx(a4, b4), umx(umx(umn(a0, b3), umn(a1, b2)),
                                       umx(umn(a2, b1), umn(a3, b0))));
    A[0]=m0; A[1]=m1; A[2]=m2; A[3]=m3; A[4]=m4;
}

// wave-wide top-5 of 64 per-lane sorted-desc 5-lists via 5x (wave-max + pop).
// Identical to butterfly multiset-merge because real keys are index-tagged
// (globally unique); only filler/zero keys duplicate across lanes and those
// can never displace real entries. [HW-verified R13: absmax unchanged]
__device__ __forceinline__ void wave_top5_2(uint32_t* ta, uint32_t* tb,
                                            uint32_t* fa, uint32_t* fb) {
#pragma unroll
    for (int k = 0; k < 5; ++k) {
        uint32_t ma = ta[0], mb = tb[0];
#pragma unroll
        for (int s = 1; s < 64; s <<= 1) {
            ma = umx(ma, __shfl_xor(ma, s, 64));
            mb = umx(mb, __shfl_xor(mb, s, 64));
        }
        fa[k] = ma; fb[k] = mb;
        if (ta[0] == ma) { ta[0]=ta[1]; ta[1]=ta[2]; ta[2]=ta[3]; ta[3]=ta[4]; ta[4]=0u; }
        if (tb[0] == mb) { tb[0]=tb[1]; tb[1]=tb[2]; tb[2]=tb[3]; tb[3]=tb[4]; tb[4]=0u; }
    }
}

__device__ __forceinline__ void wave_top5_1(uint32_t* t, uint32_t* f) {
#pragma unroll
    for (int k = 0; k < 5; ++k) {
        uint32_t m = t[0];
#pragma unroll
        for (int s = 1; s < 64; s <<= 1) m = umx(m, __shfl_xor(m, s, 64));
        f[k] = m;
        if (t[0] == m) { t[0]=t[1]; t[1]=t[2]; t[2]=t[3]; t[3]=t[4]; t[4]=0u; }
    }
}

// exact key19 = floor(it*2^19/u) + 1  (rcp seed, 1-ULP -> +/-1 fixup suffices)
__device__ __forceinline__ uint32_t jkey19(uint32_t it, uint32_t u) {
    const uint32_t n = it << 19;
    float f = (float)it * __builtin_amdgcn_rcpf((float)u) * 524288.0f;
    uint32_t ak = (uint32_t)f;
    int r = (int)(n - ak * u);
    if (r < 0) { ak--; r += (int)u; }
    if (r >= (int)u) ak++;
    return ak + 1u;
}

// ---------------- kernels ----------------

// pack labels (ballot) + row norms. 1 wave per row.
__global__ __launch_bounds__(256) void prep_kernel(const float* __restrict__ x,
                                                   const int* __restrict__ labels,
                                                   uint4* __restrict__ pk,
                                                   float* __restrict__ norms) {
    const int tid = threadIdx.x;
    const int lane = tid & 63;
    const int row = blockIdx.x * 4 + (tid >> 6);
    const int* lr = labels + (size_t)row * NLAB;
    const int la = lr[lane];
    const int lb = (lane < 16) ? lr[64 + lane] : 0;
    const u64 b0 = __ballot(la != 0);
    const u64 b1 = __ballot(lb != 0);          // lanes >=16 contribute 0
    const uint32_t w2 = (uint32_t)b1 & 0xFFFFu;
    const uint32_t cnt = (uint32_t)__popcll(b0) + (uint32_t)__popc(w2);
    if (lane == 0) pk[row] = make_uint4((uint32_t)b0, (uint32_t)(b0 >> 32), w2, cnt);
    const float* xr = x + (size_t)row * DIMS;
    float ss = 0.f;
#pragma unroll
    for (int u = 0; u < 8; ++u) { float v = xr[lane + 64 * u]; ss += v * v; }
#pragma unroll
    for (int m = 1; m < 64; m <<= 1) ss += __shfl_xor(ss, m, 64);
    if (lane == 0) norms[row] = fmaxf(sqrtf(ss), 1e-12f);
}

// FUSED kernel: one ROW-PAIR per 256-thr block (grid 2048) — R9 structure,
// with wave-max-pop top-5 extraction (R13's verified improvement) and the
// per-block blockPart partial (NO global atomics — R13's regression source).
__global__ __launch_bounds__(256) void fused_kernel(const float* __restrict__ x,
                                                    const uint4* __restrict__ pk,
                                                    const float* __restrict__ norms,
                                                    float2* __restrict__ blockPart) {
    __shared__ uint32_t segL[2][4][SEGCAP];   // 8 KB
    __shared__ uint32_t cntL[2][4];
    __shared__ uint32_t keysL[2][4][5];
    __shared__ uint32_t tgL[2][6];
    __shared__ uint32_t validL[2];
    __shared__ float    simsL[2][6];
    __shared__ float    lossW[2], cntW2[2];

    const int tid = threadIdx.x;
    const int lane = tid & 63;
    const int sub  = tid >> 6;                 // 0..3 = j-slice
    const int pr   = (int)blockIdx.x;          // [0,2048)
    const int r0 = pr, r1 = pr + HALF_ROWS;
    const uint4 P0 = pk[r0], P1 = pk[r1];
    const uint32_t cw0 = P0.w, cw1 = P1.w;
    const int jbase = sub * CHUNK;

    // ---- scan own slice, both rows of the pair ----
    uint32_t cnt0 = 0u, cnt1 = 0u;
    uint32_t t0[5], t1[5];
#pragma unroll
    for (int k = 0; k < 5; ++k) {
        const uint32_t fk = (uint32_t)(~(jbase + k)) & 0xFFFu;   // -inf fillers
        t0[k] = fk; t1[k] = fk;
    }
    uint32_t thr0 = umx(t0[4] >> 12, 1u) - 1u;
    uint32_t thr1 = umx(t1[4] >> 12, 1u) - 1u;

#pragma unroll 4
    for (int jb = 0; jb < CHUNK; jb += 64) {
        const int j = jbase + jb + lane;
        const uint4 pj = pk[j];                // L2-resident (64 KB table)
        const uint32_t cj = pj.w;
        const uint32_t jx = (~(uint32_t)j) & 0xFFFu;
        const uint32_t it0 = (uint32_t)(__popc(P0.x & pj.x) + __popc(P0.y & pj.y) + __popc(P0.z & pj.z));
        const uint32_t u0  = cw0 + cj - it0;
        const uint32_t it1 = (uint32_t)(__popc(P1.x & pj.x) + __popc(P1.y & pj.y) + __popc(P1.z & pj.z));
        const uint32_t u1  = cw1 + cj - it1;
        const bool c0 = (it0 << 1) > u0;
        const bool c1 = (it1 << 1) > u1;
        const u64 bal0 = __ballot(c0);
        const u64 bal1 = __ballot(c1);
        const u64 lmask = (1ull << lane) - 1ull;
        if (c0) {
            const uint32_t off = cnt0 + (uint32_t)__popcll(bal0 & lmask);
            if (off < SEGCAP) segL[0][sub][off] = (it0 << 20) | (u0 << 12) | (uint32_t)j;
        } else if ((it0 << 19) >= __umul24(thr0, u0)) {
            ins5_u32(t0, (jkey19(it0, u0) << 12) | jx);
            thr0 = umx(t0[4] >> 12, 1u) - 1u;
        }
        cnt0 += (uint32_t)__popcll(bal0);
        if (c1) {
            const uint32_t off = cnt1 + (uint32_t)__popcll(bal1 & lmask);
            if (off < SEGCAP) segL[1][sub][off] = (it1 << 20) | (u1 << 12) | (uint32_t)j;
        } else if ((it1 << 19) >= __umul24(thr1, u1)) {
            ins5_u32(t1, (jkey19(it1, u1) << 12) | jx);
            thr1 = umx(t1[4] >> 12, 1u) - 1u;
        }
        cnt1 += (uint32_t)__popcll(bal1);
    }
    // wave-max-pop extraction (uniform result); lane 0 publishes
    {
        uint32_t f0[5], f1[5];
        wave_top5_2(t0, t1, f0, f1);
        if (lane == 0) {
            cntL[0][sub] = cnt0; cntL[1][sub] = cnt1;
#pragma unroll
            for (int k = 0; k < 5; ++k) { keysL[0][sub][k] = f0[k]; keysL[1][sub][k] = f1[k]; }
        }
    }
    __syncthreads();

    // ---- waves 0/1: selection for row h = sub ----
    if (sub < 2) {
        const int h = sub;
        uint32_t f[5];
#pragma unroll
        for (int k = 0; k < 5; ++k) f[k] = keysL[h][0][k];
#pragma unroll
        for (int s = 1; s < 4; ++s) {
            uint32_t o[5];
#pragma unroll
            for (int k = 0; k < 5; ++k) o[k] = keysL[h][s][k];
            merge5_u32(f, o);
        }
        uint32_t ns[4];
#pragma unroll
        for (int s = 0; s < 4; ++s) ns[s] = umn(cntL[h][s], SEGCAP);

        // phase A: gumbel argmax over S entries (key19 payload in low bits)
        const uint32_t base23 = (uint32_t)pr * (uint32_t)B_ROWS;
        u64 gb = 0ull;
#pragma unroll
        for (int s = 0; s < 4; ++s) {
            for (int e = lane; e < (int)ns[s]; e += 64) {
                const uint32_t ent = segL[h][s][e];
                const uint32_t j  = ent & 0xFFFu;
                const uint32_t u  = (ent >> 12) & 0xFFu;
                const uint32_t it = ent >> 20;
                uint32_t o0, o1;
                tf2x32_key42(base23 + j, base23 + j + HCNT, o0, o1);
                const uint32_t o = h ? o1 : o0;
                const u64 key = ((u64)(o >> 9) << 41) | ((u64)((~j) & 0xFFFu) << 29) | (u64)jkey19(it, u);
                if (key > gb) gb = key;
            }
        }
#pragma unroll
        for (int m = 1; m < 64; m <<= 1) {
            const u64 o = shflx64(gb, m);
            if (o > gb) gb = o;
        }
        const bool valid = gb != 0ull;
        const int pos = valid ? (int)((~(uint32_t)(gb >> 29)) & 0xFFFu) : 0;
        const uint32_t pjkey = (uint32_t)(gb & 0xFFFFFu);

        // phase B: top-5 of S-members strictly below pj
        uint32_t ts[5] = {0u, 0u, 0u, 0u, 0u};
#pragma unroll
        for (int s = 0; s < 4; ++s) {
            for (int e = lane; e < (int)ns[s]; e += 64) {
                const uint32_t ent = segL[h][s][e];
                const uint32_t j  = ent & 0xFFFu;
                const uint32_t u  = (ent >> 12) & 0xFFu;
                const uint32_t it = ent >> 20;
                const uint32_t k19 = jkey19(it, u);
                if (k19 < pjkey) ins5_u32(ts, (k19 << 12) | ((~j) & 0xFFFu));
            }
        }
        uint32_t tsf[5];
        wave_top5_1(ts, tsf);
        merge5_u32(f, tsf);   // S keys (>0.5) outrank non-S keys; exact order

        if (lane == 0) {
            tgL[h][0] = (uint32_t)pos;
#pragma unroll
            for (int k = 0; k < 5; ++k) tgL[h][k + 1] = (~f[k]) & 0xFFFu;
            validL[h] = valid ? 1u : 0u;
        }
    }
    __syncthreads();

    // ---- 12 gather-dots, 3 per wave (identical fp order to R9) ----
#pragma unroll
    for (int k = 0; k < 3; ++k) {
        const int d = sub + 4 * k;
        const int h = (d >= 6) ? 1 : 0;
        const int q = d - 6 * h;
        const int row = h ? r1 : r0;
        const int tgt = (int)tgL[h][q];
        const float* pa = x + (size_t)row * DIMS;
        const float* pb = x + (size_t)tgt * DIMS;
        float s = 0.f;
#pragma unroll
        for (int u = 0; u < 8; ++u) s += pa[lane + 64 * u] * pb[lane + 64 * u];
#pragma unroll
        for (int m = 1; m < 64; m <<= 1) s += __shfl_xor(s, m, 64);
        if (lane == 0) simsL[h][q] = s;
    }
    __syncthreads();

    if (sub < 2 && lane == 0) {
        const int h = sub;
        float loss = 0.f, cnt = 0.f;
        if (validL[h]) {
            const int row = h ? r1 : r0;
            const float nr = norms[row];
            const float sp = simsL[h][0] / (nr * norms[tgL[h][0]]);
            float sen = 0.f;
#pragma unroll
            for (int q = 1; q < 6; ++q) sen += expf(simsL[h][q] / (nr * norms[tgL[h][q]]));
            const float ep = expf(sp);
            loss = -logf(ep / (ep + sen));
            cnt = 1.f;
        }
        lossW[h] = loss; cntW2[h] = cnt;
    }
    __syncthreads();
    if (tid == 0) blockPart[pr] = make_float2(lossW[0] + lossW[1], cntW2[0] + cntW2[1]);
}

// sum 2048 per-block partials -> scalar mean
__global__ __launch_bounds__(256) void final_kernel(const float2* __restrict__ blockPart,
                                                    float* __restrict__ out) {
    __shared__ float rl[4], rc[4];
    const int tid = threadIdx.x;
    const int lane = tid & 63;
    const int w = tid >> 6;
    float sl = 0.f, sc = 0.f;
#pragma unroll
    for (int k = 0; k < 8; ++k) {
        const float2 p = blockPart[tid + 256 * k];
        sl += p.x; sc += p.y;
    }
#pragma unroll
    for (int m = 1; m < 64; m <<= 1) {
        sl += __shfl_xor(sl, m, 64);
        sc += __shfl_xor(sc, m, 64);
    }
    if (lane == 0) { rl[w] = sl; rc[w] = sc; }
    __syncthreads();
    if (tid == 0) out[0] = (rl[0] + rl[1] + rl[2] + rl[3]) / (rc[0] + rc[1] + rc[2] + rc[3]);
}

extern "C" void kernel_launch(void* const* d_in, const int* in_sizes, int n_in,
                              void* d_out, int out_size, void* d_ws, size_t ws_size,
                              hipStream_t stream) {
    const float* x      = (const float*)d_in[0];
    const int*   labels = (const int*)d_in[1];
    float* out = (float*)d_out;

    char* ws = (char*)d_ws;
    uint4*  pk    = (uint4*)ws;                       // 64 KB
    float*  norms = (float*)(ws + 65536);             // 16 KB
    float2* bPart = (float2*)(ws + 65536 + 16384);    // 16 KB

    hipLaunchKernelGGL(prep_kernel,  dim3(1024), dim3(256), 0, stream, x, labels, pk, norms);
    hipLaunchKernelGGL(fused_kernel, dim3(2048), dim3(256), 0, stream, x, pk, norms, bPart);
    hipLaunchKernelGGL(final_kernel, dim3(1),    dim3(256), 0, stream, bPart, out);
}